// Round 9
// baseline (312.065 us; speedup 1.0000x reference)
//
#include <hip/hip_runtime.h>
#include <cstddef>

#define BATCH  4
#define SLEN   2048
#define NHEADS 16
#define DHEAD  64
#define DMODEL 1024

typedef __attribute__((ext_vector_type(8)))  short short8;   // 8 bf16 (4 VGPRs)
typedef __attribute__((ext_vector_type(4)))  float f32x4;    // 16x16 MFMA acc
typedef __attribute__((ext_vector_type(16))) float f32x16;   // 32x32 MFMA acc

// fp32 -> bf16 round-to-nearest-even
__device__ inline unsigned short f2bf(float f) {
    union { float f; unsigned int u; } v; v.f = f;
    unsigned int r = v.u + 0x7fffu + ((v.u >> 16) & 1u);
    return (unsigned short)(r >> 16);
}

__device__ inline float fast_exp2(float x) {
#if __has_builtin(__builtin_amdgcn_exp2f)
    return __builtin_amdgcn_exp2f(x);
#else
    return __expf(x * 0.69314718f);
#endif
}

// async global->LDS, 16 B per lane. LDS dest must be wave-uniform base + lane*16.
__device__ inline void gload_lds16(const unsigned short* g, unsigned short* l) {
    __builtin_amdgcn_global_load_lds(
        (const __attribute__((address_space(1))) void*)g,
        (__attribute__((address_space(3))) void*)l, 16, 0, 0);
}

// HW barrier + compiler memory fence (bare s_barrier builtin is not a
// code-motion fence; round-7/8 finding).
__device__ inline void barrier_fence() {
    asm volatile("s_barrier" ::: "memory");
}

// ---------------------------------------------------------------------------
// prep: weights only now — W fp32 [K,N] -> Wt bf16 [N,K]. The x fp32->bf16
// conversion is fused into gemm8p_qkv's A-staging (round-9 change: removes
// the 4096-block convert pass + the 33 MB xb round-trip + one dependency).
// ---------------------------------------------------------------------------
__global__ __launch_bounds__(256)
void prep(const float* __restrict__ W0, const float* __restrict__ W1,
          const float* __restrict__ W2, const float* __restrict__ W3,
          unsigned short* __restrict__ T0, unsigned short* __restrict__ T1,
          unsigned short* __restrict__ T2, unsigned short* __restrict__ T3)
{
    __shared__ unsigned short T[64 * 72];
    const int idx = blockIdx.x;
    const int tid = threadIdx.x;
    const int z = idx >> 8;
    const float* W = (z == 0) ? W0 : (z == 1) ? W1 : (z == 2) ? W2 : W3;
    unsigned short* Wt = (z == 0) ? T0 : (z == 1) ? T1 : (z == 2) ? T2 : T3;
    const int n0 = (idx & 15) * 64, k0 = ((idx >> 4) & 15) * 64;

    #pragma unroll
    for (int it = 0; it < 2; it++) {
        const int t2 = it * 256 + tid;
        const int row = t2 >> 3, col8 = (t2 & 7) * 8;
        const float4 a = *(const float4*)(W + (size_t)(k0 + row) * DMODEL + n0 + col8);
        const float4 b = *(const float4*)(W + (size_t)(k0 + row) * DMODEL + n0 + col8 + 4);
        short8 o;
        o[0] = (short)f2bf(a.x); o[1] = (short)f2bf(a.y);
        o[2] = (short)f2bf(a.z); o[3] = (short)f2bf(a.w);
        o[4] = (short)f2bf(b.x); o[5] = (short)f2bf(b.y);
        o[6] = (short)f2bf(b.z); o[7] = (short)f2bf(b.w);
        *(short8*)&T[row * 72 + col8] = o;
    }
    __syncthreads();
    #pragma unroll
    for (int it = 0; it < 2; it++) {
        const int t2 = it * 256 + tid;
        const int nn = t2 >> 3, k8 = (t2 & 7) * 8;
        short8 v;
        #pragma unroll
        for (int j = 0; j < 8; j++) v[j] = (short)T[(k8 + j) * 72 + nn];
        *(short8*)(Wt + (size_t)(n0 + nn) * DMODEL + k0 + k8) = v;
    }
}

// ---------------------------------------------------------------------------
// QKV GEMM, 256x256 tile, BK=64, 8 waves, counted-vmcnt schedule, with the
// A-operand read DIRECTLY from fp32 x and converted in-register during
// staging (reg-staged A: 2x float4 -> f2bf x8 -> ds_write_b128 per chunk).
// B stays global_load_lds. Ledger (per thread, in-order vmem retirement):
//   prologue: B(0)[4], B(1)[4], Areg(0)[8] -> WRITE_A(0) forces full retire;
//             A(0)+B(0)+B(1) in LDS before loop.
//   iter t ph0: issue Areg(t+1)[8]; NO wait (tile t guaranteed by t-1 ph3).
//   iter t ph3: vmcnt(0) retires B(t+1)+Areg(t+1) (both >=3 MFMA-phases old
//             -> near-free wait); ds_write A(t+1)->buf^1; issue B(t+2) into
//             the freed B-half; lgkmcnt(0); barrier.
// Epilogue z = bx>>2: z0 Q (pre-scaled 0.125*log2(e)) -> qb; z1 K -> kb;
// z2 V -> vtb transposed [bh][d][s].
// ---------------------------------------------------------------------------
__global__ __launch_bounds__(512, 2)
void gemm8p_qkv(const float* __restrict__ X,
                const unsigned short* __restrict__ Bw,
                unsigned short* __restrict__ qb,
                unsigned short* __restrict__ kb,
                unsigned short* __restrict__ vtb)
{
    constexpr int K = DMODEL;               // 1024
    constexpr int NT = K / 64;              // 16 K-tiles
    __shared__ unsigned short lds8[65536];  // 131072 B: As[2]@0/16384, Bs[2]@32768/49152

    const int tid  = threadIdx.x;
    const int lane = tid & 63;
    const int wave = tid >> 6;              // 0..7
    const int c  = lane & 15, qd = lane >> 4;
    const int wr = wave >> 2, wc = wave & 3;
    const int cl7 = c & 7;

    // XCD swizzle: 384 blocks, 384%8==0 -> bijective
    const int flat = blockIdx.y * 12 + blockIdx.x;
    const int swz  = (flat & 7) * 48 + (flat >> 3);
    const int bx = swz % 12, by = swz / 12;
    const int n0 = bx * 256, m0 = by * 256;

    // staging addressing: pass j covers rows cid>>3, chunk (cid&7)^(row&7)
    const float* agf[4];
    const unsigned short* bg[4];
    int lo[4];
    #pragma unroll
    for (int j = 0; j < 4; j++) {
        const int cid = j * 512 + tid;
        const int row = cid >> 3;
        const int k8  = (cid & 7) ^ (row & 7);
        agf[j] = X  + (size_t)(m0 + row) * K + k8 * 8;
        bg[j]  = Bw + (size_t)(n0 + row) * K + k8 * 8;
        lo[j] = cid * 8;
    }

    float4 ar[4][2];

#define LOAD_A() { _Pragma("unroll") \
    for (int j = 0; j < 4; j++) { \
        ar[j][0] = *(const float4*)(agf[j]); \
        ar[j][1] = *(const float4*)(agf[j] + 4); agf[j] += 64; } }
#define WRITE_A(bufi) { _Pragma("unroll") \
    for (int j = 0; j < 4; j++) { \
        short8 o; \
        o[0] = (short)f2bf(ar[j][0].x); o[1] = (short)f2bf(ar[j][0].y); \
        o[2] = (short)f2bf(ar[j][0].z); o[3] = (short)f2bf(ar[j][0].w); \
        o[4] = (short)f2bf(ar[j][1].x); o[5] = (short)f2bf(ar[j][1].y); \
        o[6] = (short)f2bf(ar[j][1].z); o[7] = (short)f2bf(ar[j][1].w); \
        *(short8*)&lds8[(bufi) * 16384 + lo[j]] = o; } }
#define STAGE_B(bufi) { _Pragma("unroll") \
    for (int j = 0; j < 4; j++) { \
        gload_lds16(bg[j], &lds8[32768 + (bufi) * 16384 + lo[j]]); bg[j] += 64; } }

    f32x4 acc[8][4];
    #pragma unroll
    for (int mb = 0; mb < 8; mb++)
        #pragma unroll
        for (int nb = 0; nb < 4; nb++)
            #pragma unroll
            for (int r = 0; r < 4; r++) acc[mb][nb][r] = 0.f;

    // prologue: B0, B1 in flight; A0 loaded+converted+written (the WRITE_A
    // data dep forces vmcnt retire of everything issued before it).
    STAGE_B(0); STAGE_B(1);
    LOAD_A();                               // Areg(0)
    WRITE_A(0);
    asm volatile("s_waitcnt lgkmcnt(0)" ::: "memory");
    barrier_fence();

    short8 bf[4], af[4];

    for (int t = 0; t < NT; t++) {
        const int buf = t & 1;
        const unsigned short* Asb = &lds8[buf * 16384];
        const unsigned short* Bsb = &lds8[32768 + buf * 16384];

        // ---- phase 0: issue Areg(t+1); bf(ks0)+af(ks0,m0-3); 16 MFMA
        if (t + 1 < NT) LOAD_A();
        {
            const int sw = qd ^ cl7;        // ks0 chunk
            #pragma unroll
            for (int nb = 0; nb < 4; nb++)
                bf[nb] = *(const short8*)&Bsb[((wc * 64 + nb * 16 + c) * 8 + sw) * 8];
            #pragma unroll
            for (int mb = 0; mb < 4; mb++)
                af[mb] = *(const short8*)&Asb[((wr * 128 + mb * 16 + c) * 8 + sw) * 8];
        }
        __builtin_amdgcn_s_setprio(1);
        #pragma unroll
        for (int mb = 0; mb < 4; mb++)
            #pragma unroll
            for (int nb = 0; nb < 4; nb++)
                acc[mb][nb] = __builtin_amdgcn_mfma_f32_16x16x32_bf16(
                    af[mb], bf[nb], acc[mb][nb], 0, 0, 0);
        __builtin_amdgcn_s_setprio(0);
        barrier_fence();

        // ---- phase 1: af(ks0,m4-7); 16 MFMA (bf ks0 in regs)
        {
            const int sw = qd ^ cl7;
            #pragma unroll
            for (int mb = 0; mb < 4; mb++)
                af[mb] = *(const short8*)&Asb[((wr * 128 + (mb + 4) * 16 + c) * 8 + sw) * 8];
        }
        __builtin_amdgcn_s_setprio(1);
        #pragma unroll
        for (int mb = 0; mb < 4; mb++)
            #pragma unroll
            for (int nb = 0; nb < 4; nb++)
                acc[mb + 4][nb] = __builtin_amdgcn_mfma_f32_16x16x32_bf16(
                    af[mb], bf[nb], acc[mb + 4][nb], 0, 0, 0);
        __builtin_amdgcn_s_setprio(0);
        barrier_fence();

        // ---- phase 2: bf(ks1)+af(ks1,m0-3); 16 MFMA
        {
            const int sw = (4 + qd) ^ cl7;  // ks1 chunk
            #pragma unroll
            for (int nb = 0; nb < 4; nb++)
                bf[nb] = *(const short8*)&Bsb[((wc * 64 + nb * 16 + c) * 8 + sw) * 8];
            #pragma unroll
            for (int mb = 0; mb < 4; mb++)
                af[mb] = *(const short8*)&Asb[((wr * 128 + mb * 16 + c) * 8 + sw) * 8];
        }
        __builtin_amdgcn_s_setprio(1);
        #pragma unroll
        for (int mb = 0; mb < 4; mb++)
            #pragma unroll
            for (int nb = 0; nb < 4; nb++)
                acc[mb][nb] = __builtin_amdgcn_mfma_f32_16x16x32_bf16(
                    af[mb], bf[nb], acc[mb][nb], 0, 0, 0);
        __builtin_amdgcn_s_setprio(0);
        barrier_fence();

        // ---- phase 3: af(ks1,m4-7); vmcnt(0) (retires B(t+1)+Areg(t+1),
        //      both >=3 phases old); write A(t+1)->buf^1; issue B(t+2) into
        //      freed B-half; lgkmcnt flush; 16 MFMA
        {
            const int sw = (4 + qd) ^ cl7;
            #pragma unroll
            for (int mb = 0; mb < 4; mb++)
                af[mb] = *(const short8*)&Asb[((wr * 128 + (mb + 4) * 16 + c) * 8 + sw) * 8];
        }
        asm volatile("s_waitcnt vmcnt(0)" ::: "memory");
        if (t + 1 < NT) WRITE_A(buf ^ 1);
        if (t + 2 < NT) STAGE_B(buf);
        asm volatile("s_waitcnt lgkmcnt(0)" ::: "memory");
        barrier_fence();
        __builtin_amdgcn_s_setprio(1);
        #pragma unroll
        for (int mb = 0; mb < 4; mb++)
            #pragma unroll
            for (int nb = 0; nb < 4; nb++)
                acc[mb + 4][nb] = __builtin_amdgcn_mfma_f32_16x16x32_bf16(
                    af[mb], bf[nb], acc[mb + 4][nb], 0, 0, 0);
        __builtin_amdgcn_s_setprio(0);
        barrier_fence();
    }
#undef LOAD_A
#undef WRITE_A
#undef STAGE_B

    // epilogue: z uniform per block (256 | 1024)
    const int z = bx >> 2;
    const int ncol0 = (n0 & 1023) + wc * 64;
    const int mbase = m0 + wr * 128 + qd * 4;
    if (z != 2) {
        unsigned short* C = z ? kb : qb;
        const float sc = z ? 1.0f : 0.18033688f;   // Q: 0.125*log2(e)
        #pragma unroll
        for (int mb = 0; mb < 8; mb++)
            #pragma unroll
            for (int nb = 0; nb < 4; nb++)
                #pragma unroll
                for (int r = 0; r < 4; r++)
                    C[(size_t)(mbase + mb * 16 + r) * DMODEL + ncol0 + nb * 16 + c] =
                        f2bf(acc[mb][nb][r] * sc);
    } else {
        #pragma unroll
        for (int mb = 0; mb < 8; mb++) {
            const int row = mbase + mb * 16;
            const int b = row >> 11, s = row & 2047;
            #pragma unroll
            for (int nb = 0; nb < 4; nb++) {
                const int n_in = ncol0 + nb * 16 + c;
                const int h = n_in >> 6, dd = n_in & 63;
                ushort4 val = make_ushort4(f2bf(acc[mb][nb][0]), f2bf(acc[mb][nb][1]),
                                           f2bf(acc[mb][nb][2]), f2bf(acc[mb][nb][3]));
                *(ushort4*)(vtb + ((size_t)((b * 16 + h) * 64 + dd)) * SLEN + s) = val;
            }
        }
    }
}

// ---------------------------------------------------------------------------
// bf16 MFMA GEMM, m97 structure — final projection only.
// C[M,N] = A[M,K] @ Wt[N,K]^T, fp32 row-major out.
// ---------------------------------------------------------------------------
__global__ __launch_bounds__(256)
void gemm_fin(const unsigned short* __restrict__ A,
              const unsigned short* __restrict__ Bw,
              float* __restrict__ C)
{
    constexpr int N = DMODEL, K = DMODEL;
    __shared__ unsigned short As[128 * 64];
    __shared__ unsigned short Bs[128 * 64];

    const int tid  = threadIdx.x;
    const int lane = tid & 63;
    const int wave = tid >> 6;
    const int c  = lane & 15, qd = lane >> 4;
    const int wr = wave >> 1, wc = wave & 1;
    const int m0 = blockIdx.y * 128, n0 = blockIdx.x * 128;

    const unsigned short* ag[4];
    const unsigned short* bg[4];
    unsigned short* al[4];
    unsigned short* bl[4];
    #pragma unroll
    for (int j = 0; j < 4; j++) {
        const int cid = j * 256 + tid;
        const int row = cid >> 3;
        const int k8  = (cid & 7) ^ (row & 7);
        ag[j] = A  + (size_t)(m0 + row) * K + k8 * 8;
        bg[j] = Bw + (size_t)(n0 + row) * K + k8 * 8;
        al[j] = &As[cid * 8];
        bl[j] = &Bs[cid * 8];
    }

    f32x4 acc[4][4];
    #pragma unroll
    for (int mb = 0; mb < 4; mb++)
        #pragma unroll
        for (int nb = 0; nb < 4; nb++)
            #pragma unroll
            for (int r = 0; r < 4; r++) acc[mb][nb][r] = 0.f;

    for (int k0 = 0; k0 < K; k0 += 64) {
        __syncthreads();
        #pragma unroll
        for (int j = 0; j < 4; j++) {
            gload_lds16(ag[j], al[j]);
            gload_lds16(bg[j], bl[j]);
            ag[j] += 64; bg[j] += 64;
        }
        __syncthreads();

        #pragma unroll
        for (int ks = 0; ks < 2; ks++) {
            const int sw = (ks * 4 + qd) ^ (c & 7);
            short8 af[4], bf[4];
            #pragma unroll
            for (int mb = 0; mb < 4; mb++)
                af[mb] = *(const short8*)&As[((wr * 64 + mb * 16 + c) * 8 + sw) * 8];
            #pragma unroll
            for (int nb = 0; nb < 4; nb++)
                bf[nb] = *(const short8*)&Bs[((wc * 64 + nb * 16 + c) * 8 + sw) * 8];
            #pragma unroll
            for (int mb = 0; mb < 4; mb++)
                #pragma unroll
                for (int nb = 0; nb < 4; nb++)
                    acc[mb][nb] = __builtin_amdgcn_mfma_f32_16x16x32_bf16(
                        af[mb], bf[nb], acc[mb][nb], 0, 0, 0);
        }
    }

    const int mbase = m0 + wr * 64 + qd * 4;
    const int nbase = n0 + wc * 64 + c;
    #pragma unroll
    for (int mb = 0; mb < 4; mb++)
        #pragma unroll
        for (int nb = 0; nb < 4; nb++)
            #pragma unroll
            for (int r = 0; r < 4; r++)
                C[(size_t)(mbase + mb * 16 + r) * N + nbase + nb * 16] = acc[mb][nb][r];
}

// ---------------------------------------------------------------------------
// MFMA bf16 flash attention v6 (the attn local optimum per rounds 1-5):
// 32 q/wave, 128 q per block, 1024 blocks = 4 blocks/CU. K/V staged in LDS
// (reuse-1). Q pre-scaled in the QKV GEMM. XCD-bijective swizzle.
// ---------------------------------------------------------------------------
__global__ __launch_bounds__(256, 4)
void attn_mfma6(const unsigned short* __restrict__ qb,
                const unsigned short* __restrict__ kb,
                const unsigned short* __restrict__ vtb,
                unsigned short* __restrict__ O)
{
    __shared__ unsigned short lds[18432];   // 36864 B
    unsigned short* Ks = lds;               // 64 keys x 8 chunks (swizzled, rows permuted)
    unsigned short* Vs = lds + 4096;        // 64 d    x 8 chunks (swizzled)

    const int tid = threadIdx.x;
    const int w   = tid >> 6, ln = tid & 63;
    const int c5  = ln & 31;
    const int l5i = ln >> 5;

    const int L  = blockIdx.x + (int)gridDim.x * blockIdx.y;
    const int wg = (L & 7) * 128 + (L >> 3);
    const int qt = wg & 15, bh = wg >> 4;
    const int b = bh >> 4, h = bh & 15;
    const size_t bh_base = ((size_t)b * SLEN * NHEADS + h) * 64;
    constexpr int RS = NHEADS * 64;                 // 1024

    const int srow = ln >> 3;
    const int sk8  = (ln & 7) ^ srow;
    const int prow = (srow & 3) | ((w & 1) << 2) | (((srow >> 2) & 1) << 3) | ((w >> 1) << 4);
    const unsigned short* kg0 = kb + bh_base + (size_t)prow * RS + sk8 * 8;
    const unsigned short* kg1 = kg0 + (size_t)32 * RS;
    const unsigned short* vg0 = vtb + ((size_t)bh * 64 + w * 8 + srow) * SLEN + sk8 * 8;
    const unsigned short* vg1 = vg0 + (size_t)32 * SLEN;
    unsigned short* kl0 = &Ks[(w * 64 + ln) * 8];
    unsigned short* kl1 = kl0 + 2048;
    unsigned short* vl0 = &Vs[(w * 64 + ln) * 8];
    unsigned short* vl1 = vl0 + 2048;

    const int qtile = qt * 128 + w * 32;

    short8 qf[4];
    #pragma unroll
    for (int kst = 0; kst < 4; kst++)
        qf[kst] = *(const short8*)(qb + bh_base +
            (size_t)(qtile + c5) * RS + kst * 16 + l5i * 8);

    f32x16 acc[2];                          // [db32]
    #pragma unroll
    for (int db = 0; db < 2; db++)
        #pragma unroll
        for (int r = 0; r < 16; r++) acc[db][r] = 0.f;
    float lsum = 0.f;
    const int cl7 = c5 & 7;

    for (int kt = 0; kt < SLEN / 64; kt++) {
        __syncthreads();                    // prev tile's K/V reads done
        gload_lds16(kg0, kl0); gload_lds16(kg1, kl1);
        gload_lds16(vg0, vl0); gload_lds16(vg1, vl1);
        kg0 += (size_t)64 * RS; kg1 += (size_t)64 * RS; vg0 += 64; vg1 += 64;
        __syncthreads();                    // vmcnt drain: LDS populated

        #pragma unroll
        for (int kb32 = 0; kb32 < 2; kb32++) {
            f32x16 sacc;
            #pragma unroll
            for (int r = 0; r < 16; r++) sacc[r] = 0.f;
            __builtin_amdgcn_s_setprio(1);
            #pragma unroll
            for (int kst = 0; kst < 4; kst++) {
                const int slot = (kst * 2 + l5i) ^ cl7;
                short8 kf = *(const short8*)&Ks[((kb32 * 32 + c5) * 8 + slot) * 8];
                sacc = __builtin_amdgcn_mfma_f32_32x32x16_bf16(
                    kf, qf[kst], sacc, 0, 0, 0);
            }
            __builtin_amdgcn_s_setprio(0);

            unsigned pk[8];
            {
                float p[16];
                float s0 = 0.f, s1 = 0.f;
                #pragma unroll
                for (int r = 0; r < 16; r += 2) {
                    p[r]     = fast_exp2(sacc[r]);
                    p[r + 1] = fast_exp2(sacc[r + 1]);
                    s0 += p[r]; s1 += p[r + 1];
                }
                lsum += s0 + s1;
                #pragma unroll
                for (int i = 0; i < 8; i++)
                    pk[i] = __builtin_amdgcn_perm(
                        __float_as_uint(p[2 * i + 1]), __float_as_uint(p[2 * i]),
                        0x07060302u);
            }

            #pragma unroll
            for (int kk = 0; kk < 2; kk++) {
                const int k2 = kb32 * 2 + kk;
                union { unsigned u[4]; short8 s; } t;
                t.u[0] = pk[4 * kk + 0];
                t.u[1] = pk[4 * kk + 1];
                t.u[2] = pk[4 * kk + 2];
                t.u[3] = pk[4 * kk + 3];
                const short8 pf = t.s;
                __builtin_amdgcn_s_setprio(1);
                #pragma unroll
                for (int db = 0; db < 2; db++) {
                    const int slot = (k2 * 2 + l5i) ^ cl7;
                    short8 vf = *(const short8*)&Vs[((db * 32 + c5) * 8 + slot) * 8];
                    acc[db] = __builtin_amdgcn_mfma_f32_32x32x16_bf16(
                        vf, pf, acc[db], 0, 0, 0);
                }
                __builtin_amdgcn_s_setprio(0);
            }
        }
    }

    __syncthreads();                        // all waves done with Ks/Vs
    float l = lsum;
    l += __shfl_xor(l, 32);
    const float inv = 1.001953125f / l;     // (1+2^-9) truncation compensation
    unsigned short* E = lds + w * 2304;     // 32 x 72 bf16 per wave
    #pragma unroll
    for (int db = 0; db < 2; db++)
        #pragma unroll
        for (int u = 0; u < 4; u++) {
            const int d0 = db * 32 + 8 * u + 4 * l5i;
            const int q  = c5;
            ushort4 val = make_ushort4(
                f2bf(acc[db][4 * u + 0] * inv),
                f2bf(acc[db][4 * u + 1] * inv),
                f2bf(acc[db][4 * u + 2] * inv),
                f2bf(acc[db][4 * u + 3] * inv));
            *(ushort4*)&E[q * 72 + d0] = val;
        }
    __builtin_amdgcn_wave_barrier();        // wave-private region, in-order DS
    #pragma unroll
    for (int it = 0; it < 4; it++) {
        const int t2 = it * 64 + ln;
        const int row = t2 >> 3, col8 = (t2 & 7) * 8;
        short8 o = *(const short8*)&E[row * 72 + col8];
        *(short8*)(O + bh_base + (size_t)(qtile + row) * RS + col8) = o;
    }
}

// ---------------------------------------------------------------------------
extern "C" void kernel_launch(void* const* d_in, const int* in_sizes, int n_in,
                              void* d_out, int out_size, void* d_ws, size_t ws_size,
                              hipStream_t stream)
{
    const float* x  = (const float*)d_in[0];
    const float* Wq = (const float*)d_in[1];
    const float* Wk = (const float*)d_in[2];
    const float* Wv = (const float*)d_in[3];
    const float* Wo = (const float*)d_in[4];
    float* out = (float*)d_out;

    const size_t per = (size_t)BATCH * SLEN * NHEADS * DHEAD;  // 8,388,608 elems
    const size_t wsz = (size_t)DMODEL * DMODEL;
    unsigned short* qb  = (unsigned short*)d_ws;  // bf16 [b][s][h][d]; attn out aliases
    unsigned short* kb  = qb  + per;
    unsigned short* vtb = kb  + per;              // bf16 [bh][d][s]
    unsigned short* wtq = vtb + per;              // bf16 [N][K] x4 (contiguous -> fused B)
    unsigned short* wtk = wtq + wsz;
    unsigned short* wtv = wtk + wsz;
    unsigned short* wto = wtv + wsz;
    // ws use: (3*per + 4*wsz)*2 = 58,720,256 B (xb eliminated)

    prep<<<dim3(1024), dim3(256), 0, stream>>>(Wq, Wk, Wv, Wo,
                                               wtq, wtk, wtv, wto);

    // fused QKV: A read directly from fp32 x (in-register convert);
    // B = [3072][1024] (wtq..wtv contiguous); grid 12x32 = 384 blocks
    gemm8p_qkv<<<dim3(12, 32), dim3(512), 0, stream>>>(x, wtq, qb, kb, vtb);

    attn_mfma6<<<dim3(SLEN / 128, BATCH * NHEADS), dim3(256), 0, stream>>>(qb, kb, vtb, qb);

    gemm_fin<<<dim3(8, 64), dim3(256), 0, stream>>>(qb, wto, out);
}

// Round 10
// 256.600 us; speedup vs baseline: 1.2162x; 1.2162x over previous
//
#include <hip/hip_runtime.h>
#include <cstddef>

#define BATCH  4
#define SLEN   2048
#define NHEADS 16
#define DHEAD  64
#define DMODEL 1024

typedef __attribute__((ext_vector_type(8)))  short short8;   // 8 bf16 (4 VGPRs)
typedef __attribute__((ext_vector_type(4)))  float f32x4;    // 16x16 MFMA acc
typedef __attribute__((ext_vector_type(16))) float f32x16;   // 32x32 MFMA acc

// fp32 -> bf16 round-to-nearest-even
__device__ inline unsigned short f2bf(float f) {
    union { float f; unsigned int u; } v; v.f = f;
    unsigned int r = v.u + 0x7fffu + ((v.u >> 16) & 1u);
    return (unsigned short)(r >> 16);
}

__device__ inline float fast_exp2(float x) {
#if __has_builtin(__builtin_amdgcn_exp2f)
    return __builtin_amdgcn_exp2f(x);
#else
    return __expf(x * 0.69314718f);
#endif
}

// async global->LDS, 16 B per lane. LDS dest must be wave-uniform base + lane*16.
__device__ inline void gload_lds16(const unsigned short* g, unsigned short* l) {
    __builtin_amdgcn_global_load_lds(
        (const __attribute__((address_space(1))) void*)g,
        (__attribute__((address_space(3))) void*)l, 16, 0, 0);
}

// ---------------------------------------------------------------------------
// prep: fused x fp32->bf16 convert (blocks 0..4095) + weight transpose+convert
// (blocks 4096..5119).
// ---------------------------------------------------------------------------
__global__ __launch_bounds__(256)
void prep(const float* __restrict__ x, unsigned short* __restrict__ xb,
          const float* __restrict__ W0, const float* __restrict__ W1,
          const float* __restrict__ W2, const float* __restrict__ W3,
          unsigned short* __restrict__ T0, unsigned short* __restrict__ T1,
          unsigned short* __restrict__ T2, unsigned short* __restrict__ T3)
{
    __shared__ unsigned short T[64 * 72];
    const int bid = blockIdx.x;
    const int tid = threadIdx.x;

    if (bid < 4096) {                       // ---- convert part ----
        const int i = bid * 256 + tid;      // n8 = 1048576, exact fit
        const float4 a = ((const float4*)x)[2 * i];
        const float4 b = ((const float4*)x)[2 * i + 1];
        short8 o;
        o[0] = (short)f2bf(a.x); o[1] = (short)f2bf(a.y);
        o[2] = (short)f2bf(a.z); o[3] = (short)f2bf(a.w);
        o[4] = (short)f2bf(b.x); o[5] = (short)f2bf(b.y);
        o[6] = (short)f2bf(b.z); o[7] = (short)f2bf(b.w);
        ((short8*)xb)[i] = o;
        return;
    }

    // ---- wtrans part: W fp32 [K,N] -> Wt bf16 [N,K] ----
    const int idx = bid - 4096;
    const int z = idx >> 8;
    const float* W = (z == 0) ? W0 : (z == 1) ? W1 : (z == 2) ? W2 : W3;
    unsigned short* Wt = (z == 0) ? T0 : (z == 1) ? T1 : (z == 2) ? T2 : T3;
    const int n0 = (idx & 15) * 64, k0 = ((idx >> 4) & 15) * 64;

    #pragma unroll
    for (int it = 0; it < 2; it++) {
        const int t2 = it * 256 + tid;
        const int row = t2 >> 3, col8 = (t2 & 7) * 8;
        const float4 a = *(const float4*)(W + (size_t)(k0 + row) * DMODEL + n0 + col8);
        const float4 b = *(const float4*)(W + (size_t)(k0 + row) * DMODEL + n0 + col8 + 4);
        short8 o;
        o[0] = (short)f2bf(a.x); o[1] = (short)f2bf(a.y);
        o[2] = (short)f2bf(a.z); o[3] = (short)f2bf(a.w);
        o[4] = (short)f2bf(b.x); o[5] = (short)f2bf(b.y);
        o[6] = (short)f2bf(b.z); o[7] = (short)f2bf(b.w);
        *(short8*)&T[row * 72 + col8] = o;
    }
    __syncthreads();
    #pragma unroll
    for (int it = 0; it < 2; it++) {
        const int t2 = it * 256 + tid;
        const int nn = t2 >> 3, k8 = (t2 & 7) * 8;
        short8 v;
        #pragma unroll
        for (int j = 0; j < 8; j++) v[j] = (short)T[(k8 + j) * 72 + nn];
        *(short8*)(Wt + (size_t)(n0 + nn) * DMODEL + k0 + k8) = v;
    }
}

// ---------------------------------------------------------------------------
// bf16 MFMA GEMM, m97 structure. C[M,N] = A[M,K] @ Wt[N,K]^T.
// Round-10 change: XCD-aware block swizzle with z-adjacency. Blocks are
// remapped from the flat hw id so each XCD owns 8 contiguous by-rows, and
// within one by-group all (z,bx) blocks run on the same XCD -> the 1 MB
// A-slab is fetched into that XCD's L2 once and reused 24x (KIND=0) / 8x
// (KIND=1) instead of scattering across 8 XCDs.
// KIND=0: z==0 Q (pre-scaled 0.125*log2(e)); z==1 K; z==2 V^T via LDS
// transpose (coalesced 256 B row writes). KIND=1: fp32 final projection.
// ---------------------------------------------------------------------------
template<int KIND>
__global__ __launch_bounds__(256)
void gemm_bf16(const unsigned short* __restrict__ A,
               const unsigned short* __restrict__ B0,
               const unsigned short* __restrict__ B1,
               const unsigned short* __restrict__ B2,
               void* __restrict__ C0v, void* __restrict__ C1v, void* __restrict__ C2v)
{
    constexpr int N = DMODEL, K = DMODEL;
    // 17408 shorts = 34816 B. Staging: As = lds[0..8191], Bs = lds[8192..16383].
    // z==2 epilogue reuses the whole buffer as T[128][136] (after barrier).
    __shared__ unsigned short lds[17408];
    unsigned short* As = lds;
    unsigned short* Bs = lds + 8192;

    // XCD swizzle + z-adjacency (bijective: 1536 = 8 xcd x 8 by x 3 z x 8 bx;
    // 512 = 8 x 8 x 8 for KIND=1).
    int bx, by, z;
    {
        const int flat = blockIdx.x + (int)gridDim.x * (blockIdx.y + (int)gridDim.y * blockIdx.z);
        const int xcd = flat & 7;
        const int idx = flat >> 3;
        if (KIND == 0) {
            by = xcd * 8 + idx / 24;
            const int rem = idx % 24;
            z = rem >> 3; bx = rem & 7;
        } else {
            by = xcd * 8 + (idx >> 3);
            z = 0; bx = idx & 7;
        }
    }

    const unsigned short* Bw = (z == 0) ? B0 : (z == 1) ? B1 : B2;
    void* Cv = (z == 0) ? C0v : (z == 1) ? C1v : C2v;

    const int tid  = threadIdx.x;
    const int lane = tid & 63;
    const int wave = tid >> 6;
    const int c  = lane & 15, qd = lane >> 4;
    const int wr = wave >> 1, wc = wave & 1;
    const int m0 = by * 128, n0 = bx * 128;

    const unsigned short* ag[4];
    const unsigned short* bg[4];
    unsigned short* al[4];
    unsigned short* bl[4];
    #pragma unroll
    for (int j = 0; j < 4; j++) {
        const int cid = j * 256 + tid;
        const int row = cid >> 3;
        const int k8  = (cid & 7) ^ (row & 7);
        ag[j] = A  + (size_t)(m0 + row) * K + k8 * 8;
        bg[j] = Bw + (size_t)(n0 + row) * K + k8 * 8;
        al[j] = &As[cid * 8];
        bl[j] = &Bs[cid * 8];
    }

    f32x4 acc[4][4];
    #pragma unroll
    for (int mb = 0; mb < 4; mb++)
        #pragma unroll
        for (int nb = 0; nb < 4; nb++)
            #pragma unroll
            for (int r = 0; r < 4; r++) acc[mb][nb][r] = 0.f;

    for (int k0 = 0; k0 < K; k0 += 64) {
        __syncthreads();
        #pragma unroll
        for (int j = 0; j < 4; j++) {
            gload_lds16(ag[j], al[j]);
            gload_lds16(bg[j], bl[j]);
            ag[j] += 64; bg[j] += 64;
        }
        __syncthreads();

        #pragma unroll
        for (int ks = 0; ks < 2; ks++) {
            const int sw = (ks * 4 + qd) ^ (c & 7);
            short8 af[4], bf[4];
            #pragma unroll
            for (int mb = 0; mb < 4; mb++)
                af[mb] = *(const short8*)&As[((wr * 64 + mb * 16 + c) * 8 + sw) * 8];
            #pragma unroll
            for (int nb = 0; nb < 4; nb++)
                bf[nb] = *(const short8*)&Bs[((wc * 64 + nb * 16 + c) * 8 + sw) * 8];
            #pragma unroll
            for (int mb = 0; mb < 4; mb++)
                #pragma unroll
                for (int nb = 0; nb < 4; nb++)
                    acc[mb][nb] = __builtin_amdgcn_mfma_f32_16x16x32_bf16(
                        af[mb], bf[nb], acc[mb][nb], 0, 0, 0);
        }
    }

    const int mbase = m0 + wr * 64 + qd * 4;
    const int nbase = n0 + wc * 64 + c;
    if (KIND == 1) {
        float* C = (float*)Cv;
        #pragma unroll
        for (int mb = 0; mb < 4; mb++)
            #pragma unroll
            for (int nb = 0; nb < 4; nb++)
                #pragma unroll
                for (int r = 0; r < 4; r++)
                    C[(size_t)(mbase + mb * 16 + r) * N + nbase + nb * 16] = acc[mb][nb][r];
    } else if (z != 2) {
        unsigned short* C = (unsigned short*)Cv;
        const float osc = (z == 0) ? 0.18033688f : 1.0f;  // Q: 0.125*log2(e)
        #pragma unroll
        for (int mb = 0; mb < 4; mb++)
            #pragma unroll
            for (int nb = 0; nb < 4; nb++)
                #pragma unroll
                for (int r = 0; r < 4; r++)
                    C[(size_t)(mbase + mb * 16 + r) * N + nbase + nb * 16] =
                        f2bf(acc[mb][nb][r] * osc);
    } else {
        // V^T via LDS transpose: stage C-tile as T[n_local][m_local] bf16
        // (stride 136 shorts -> 16B-aligned rows), then coalesced 256 B row
        // writes to vtb[(b*16+h)*64+dd][s].
        __syncthreads();                     // all waves done with As/Bs
        unsigned short* T = lds;             // [128][136]
        #pragma unroll
        for (int mb = 0; mb < 4; mb++) {
            const int sl = wr * 64 + qd * 4 + mb * 16;   // local m 0..127
            #pragma unroll
            for (int nb = 0; nb < 4; nb++) {
                const int dl = wc * 64 + nb * 16 + c;    // local n 0..127
                ushort4 val = make_ushort4(f2bf(acc[mb][nb][0]), f2bf(acc[mb][nb][1]),
                                           f2bf(acc[mb][nb][2]), f2bf(acc[mb][nb][3]));
                *(ushort4*)&T[dl * 136 + sl] = val;
            }
        }
        __syncthreads();
        unsigned short* C = (unsigned short*)Cv;
        const int b  = m0 >> 11;
        const int s0 = m0 & 2047;
        #pragma unroll
        for (int it = 0; it < 8; it++) {
            const int chunk = it * 256 + tid;
            const int row  = chunk >> 4;           // local n 0..127
            const int col8 = (chunk & 15) * 8;     // local m offset
            const int n = n0 + row;
            const int h2 = n >> 6, dd = n & 63;
            short8 v = *(const short8*)&T[row * 136 + col8];
            *(short8*)(C + ((size_t)((b * 16 + h2) * 64 + dd)) * SLEN + s0 + col8) = v;
        }
    }
}

// ---------------------------------------------------------------------------
// MFMA bf16 flash attention v6 (the attn local optimum per rounds 1-5):
// 32 q/wave, 128 q per block, 1024 blocks = 4 blocks/CU. K/V staged in LDS
// (reuse-1). Q pre-scaled in the QKV GEMM. XCD-bijective swizzle.
// ---------------------------------------------------------------------------
__global__ __launch_bounds__(256, 4)
void attn_mfma6(const unsigned short* __restrict__ qb,
                const unsigned short* __restrict__ kb,
                const unsigned short* __restrict__ vtb,
                unsigned short* __restrict__ O)
{
    __shared__ unsigned short lds[18432];   // 36864 B
    unsigned short* Ks = lds;               // 64 keys x 8 chunks (swizzled, rows permuted)
    unsigned short* Vs = lds + 4096;        // 64 d    x 8 chunks (swizzled)

    const int tid = threadIdx.x;
    const int w   = tid >> 6, ln = tid & 63;
    const int c5  = ln & 31;
    const int l5i = ln >> 5;

    const int L  = blockIdx.x + (int)gridDim.x * blockIdx.y;
    const int wg = (L & 7) * 128 + (L >> 3);
    const int qt = wg & 15, bh = wg >> 4;
    const int b = bh >> 4, h = bh & 15;
    const size_t bh_base = ((size_t)b * SLEN * NHEADS + h) * 64;
    constexpr int RS = NHEADS * 64;                 // 1024

    const int srow = ln >> 3;
    const int sk8  = (ln & 7) ^ srow;
    const int prow = (srow & 3) | ((w & 1) << 2) | (((srow >> 2) & 1) << 3) | ((w >> 1) << 4);
    const unsigned short* kg0 = kb + bh_base + (size_t)prow * RS + sk8 * 8;
    const unsigned short* kg1 = kg0 + (size_t)32 * RS;
    const unsigned short* vg0 = vtb + ((size_t)bh * 64 + w * 8 + srow) * SLEN + sk8 * 8;
    const unsigned short* vg1 = vg0 + (size_t)32 * SLEN;
    unsigned short* kl0 = &Ks[(w * 64 + ln) * 8];
    unsigned short* kl1 = kl0 + 2048;
    unsigned short* vl0 = &Vs[(w * 64 + ln) * 8];
    unsigned short* vl1 = vl0 + 2048;

    const int qtile = qt * 128 + w * 32;

    short8 qf[4];
    #pragma unroll
    for (int kst = 0; kst < 4; kst++)
        qf[kst] = *(const short8*)(qb + bh_base +
            (size_t)(qtile + c5) * RS + kst * 16 + l5i * 8);

    f32x16 acc[2];                          // [db32]
    #pragma unroll
    for (int db = 0; db < 2; db++)
        #pragma unroll
        for (int r = 0; r < 16; r++) acc[db][r] = 0.f;
    float lsum = 0.f;
    const int cl7 = c5 & 7;

    for (int kt = 0; kt < SLEN / 64; kt++) {
        __syncthreads();                    // prev tile's K/V reads done
        gload_lds16(kg0, kl0); gload_lds16(kg1, kl1);
        gload_lds16(vg0, vl0); gload_lds16(vg1, vl1);
        kg0 += (size_t)64 * RS; kg1 += (size_t)64 * RS; vg0 += 64; vg1 += 64;
        __syncthreads();                    // vmcnt drain: LDS populated

        #pragma unroll
        for (int kb32 = 0; kb32 < 2; kb32++) {
            f32x16 sacc;
            #pragma unroll
            for (int r = 0; r < 16; r++) sacc[r] = 0.f;
            __builtin_amdgcn_s_setprio(1);
            #pragma unroll
            for (int kst = 0; kst < 4; kst++) {
                const int slot = (kst * 2 + l5i) ^ cl7;
                short8 kf = *(const short8*)&Ks[((kb32 * 32 + c5) * 8 + slot) * 8];
                sacc = __builtin_amdgcn_mfma_f32_32x32x16_bf16(
                    kf, qf[kst], sacc, 0, 0, 0);
            }
            __builtin_amdgcn_s_setprio(0);

            unsigned pk[8];
            {
                float p[16];
                float s0 = 0.f, s1 = 0.f;
                #pragma unroll
                for (int r = 0; r < 16; r += 2) {
                    p[r]     = fast_exp2(sacc[r]);
                    p[r + 1] = fast_exp2(sacc[r + 1]);
                    s0 += p[r]; s1 += p[r + 1];
                }
                lsum += s0 + s1;
                #pragma unroll
                for (int i = 0; i < 8; i++)
                    pk[i] = __builtin_amdgcn_perm(
                        __float_as_uint(p[2 * i + 1]), __float_as_uint(p[2 * i]),
                        0x07060302u);
            }

            #pragma unroll
            for (int kk = 0; kk < 2; kk++) {
                const int k2 = kb32 * 2 + kk;
                union { unsigned u[4]; short8 s; } t;
                t.u[0] = pk[4 * kk + 0];
                t.u[1] = pk[4 * kk + 1];
                t.u[2] = pk[4 * kk + 2];
                t.u[3] = pk[4 * kk + 3];
                const short8 pf = t.s;
                __builtin_amdgcn_s_setprio(1);
                #pragma unroll
                for (int db = 0; db < 2; db++) {
                    const int slot = (k2 * 2 + l5i) ^ cl7;
                    short8 vf = *(const short8*)&Vs[((db * 32 + c5) * 8 + slot) * 8];
                    acc[db] = __builtin_amdgcn_mfma_f32_32x32x16_bf16(
                        vf, pf, acc[db], 0, 0, 0);
                }
                __builtin_amdgcn_s_setprio(0);
            }
        }
    }

    __syncthreads();                        // all waves done with Ks/Vs
    float l = lsum;
    l += __shfl_xor(l, 32);
    const float inv = 1.001953125f / l;     // (1+2^-9) truncation compensation
    unsigned short* E = lds + w * 2304;     // 32 x 72 bf16 per wave
    #pragma unroll
    for (int db = 0; db < 2; db++)
        #pragma unroll
        for (int u = 0; u < 4; u++) {
            const int d0 = db * 32 + 8 * u + 4 * l5i;
            const int q  = c5;
            ushort4 val = make_ushort4(
                f2bf(acc[db][4 * u + 0] * inv),
                f2bf(acc[db][4 * u + 1] * inv),
                f2bf(acc[db][4 * u + 2] * inv),
                f2bf(acc[db][4 * u + 3] * inv));
            *(ushort4*)&E[q * 72 + d0] = val;
        }
    __builtin_amdgcn_wave_barrier();        // wave-private region, in-order DS
    #pragma unroll
    for (int it = 0; it < 4; it++) {
        const int t2 = it * 64 + ln;
        const int row = t2 >> 3, col8 = (t2 & 7) * 8;
        short8 o = *(const short8*)&E[row * 72 + col8];
        *(short8*)(O + bh_base + (size_t)(qtile + row) * RS + col8) = o;
    }
}

// ---------------------------------------------------------------------------
extern "C" void kernel_launch(void* const* d_in, const int* in_sizes, int n_in,
                              void* d_out, int out_size, void* d_ws, size_t ws_size,
                              hipStream_t stream)
{
    const float* x  = (const float*)d_in[0];
    const float* Wq = (const float*)d_in[1];
    const float* Wk = (const float*)d_in[2];
    const float* Wv = (const float*)d_in[3];
    const float* Wo = (const float*)d_in[4];
    float* out = (float*)d_out;

    const size_t per = (size_t)BATCH * SLEN * NHEADS * DHEAD;  // 8,388,608 elems
    const size_t wsz = (size_t)DMODEL * DMODEL;
    unsigned short* qb  = (unsigned short*)d_ws;  // bf16 [b][s][h][d]; attn out aliases
    unsigned short* kb  = qb  + per;
    unsigned short* vtb = kb  + per;              // bf16 [bh][d][s]
    unsigned short* xb  = vtb + per;              // bf16 [M][K]
    unsigned short* wtq = xb  + per;              // bf16 [N][K] x4
    unsigned short* wtk = wtq + wsz;
    unsigned short* wtv = wtk + wsz;
    unsigned short* wto = wtv + wsz;
    // ws use: (4*per + 4*wsz)*2 = 75,497,472 B

    dim3 blk(256);
    prep<<<dim3(4096 + 1024), blk, 0, stream>>>(x, xb, Wq, Wk, Wv, Wo,
                                                wtq, wtk, wtv, wto);

    gemm_bf16<0><<<dim3(8, 64, 3), blk, 0, stream>>>(xb, wtq, wtk, wtv, qb, kb, vtb);

    attn_mfma6<<<dim3(SLEN / 128, BATCH * NHEADS), blk, 0, stream>>>(qb, kb, vtb, qb);

    gemm_bf16<1><<<dim3(8, 64, 1), blk, 0, stream>>>(qb, wto, wto, wto, out, out, out);
}